// Round 6
// baseline (9249.457 us; speedup 1.0000x reference)
//
#include <hip/hip_runtime.h>
#include <hip/hip_bf16.h>

#define TT 512
#define NB 1024

typedef float f32x4 __attribute__((ext_vector_type(4)));
typedef __bf16 bf16x8 __attribute__((ext_vector_type(8)));
typedef __bf16 bf16x4 __attribute__((ext_vector_type(4)));

// ---- workspace layout (bf16 elems). All matrices stored as A-fragments for
// the TRANSPOSED GEMM  C^T[feature][batch] = W^T @ act^T :
//   frag(mt, kt, lane, j) at ((mt*KT + kt)*512 + lane*8 + j)
//   value = W[kappa][16*mt + (lane&15)]
// For weights consuming register-resident activations (Whp, Wm, Whpost, Wr1):
//   kappa = 32*kt + 16*(j>>2) + 4*(lane>>4) + (j&3)  [pi-permutation: B-frag ==
//   accumulator contents of the producing stage]. For Wcp (consumes x):
//   kappa = 32*kt + 8*(lane>>4) + j (natural).
#define OFF_HP 0
#define OFF_CP 65536
#define OFF_M  81920
#define OFF_PO 212992
#define OFF_R1 278528
#define TOT    344064

__global__ __launch_bounds__(256) void pack_weights(
    const float* __restrict__ Whp, const float* __restrict__ Wm,
    const float* __restrict__ Wcp, const float* __restrict__ Whpost,
    const float* __restrict__ Wr1, __bf16* __restrict__ wsp) {
  int id = blockIdx.x * 256 + threadIdx.x;
  if (id >= TOT) return;
  int j = id & 7, lane = (id >> 3) & 63;
  int lq = lane >> 4, l15 = lane & 15;
  int rel, KT; const float* W; bool perm = true;
  if (id < OFF_CP)      { rel = id;          KT = 8;  W = Whp; }
  else if (id < OFF_M)  { rel = id - OFF_CP; KT = 2;  W = Wcp; perm = false; }
  else if (id < OFF_PO) { rel = id - OFF_M;  KT = 16; W = Wm; }
  else if (id < OFF_R1) { rel = id - OFF_PO; KT = 8;  W = Whpost; }
  else                  { rel = id - OFF_R1; KT = 8;  W = Wr1; }
  int ktm = rel >> 9;
  int kt = ktm % KT, mt = ktm / KT;
  int phi = 16 * mt + l15;
  int kk;
  if (perm) {
    int kb = (kt >= 8) ? kt - 8 : kt;          // only mesh has kt>=8
    kk = 32 * kb + 16 * (j >> 2) + 4 * lq + (j & 3);
    if (kt >= 8) kk += 256;                    // cp half of the concat
  } else {
    kk = 32 * kt + 8 * lq + j;
  }
  wsp[id] = (__bf16)W[kk * 256 + phi];
}

__device__ __forceinline__ float tanh_fast(float x) {
  float t = __expf(2.0f * x);
  return 1.0f - __fdividef(2.0f, t + 1.0f);
}

#define MFMA(a, b, c) __builtin_amdgcn_mfma_f32_16x16x32_bf16((a), (b), (c), 0, 0, 0)

// Wave owning m-tile mt packs its accumulator (4 features x batch) into the
// j-half of B-fragment kt = mt>>1: pure in-lane, conflict-light ds_write_b64.
__device__ __forceinline__ void pack4(__bf16* region, int mt, int lane,
                                      const f32x4& a) {
  bf16x4 f;
  #pragma unroll
  for (int r = 0; r < 4; ++r) f[r] = (__bf16)tanh_fast(a[r]);
  *(bf16x4*)(region + (mt >> 1) * 512 + lane * 8 + 4 * (mt & 1)) = f;
}

__global__ __launch_bounds__(1024, 4)
__attribute__((amdgpu_waves_per_eu(4, 4)))   // pin: 128-VGPR budget, no drift
void rnn_seq(
    const float* __restrict__ x, const __bf16* __restrict__ wsp,
    const float* __restrict__ bhp, const float* __restrict__ bcp,
    const float* __restrict__ bm, const float* __restrict__ bhpost,
    const float* __restrict__ br1, const float* __restrict__ Wr2,
    const float* __restrict__ br2, float* __restrict__ out) {
  __shared__ __align__(16) __bf16 hB[8 * 512];   // h state as B-frags
  __shared__ __align__(16) __bf16 mB[16 * 512];  // [hpB | cpB] for mesh
  __shared__ __align__(16) __bf16 uB[8 * 512];   // mesh output
  __shared__ float lb[6 * 256];                  // bhp,bcp,bm,bhpost,br1,Wr2
  __shared__ float outp[256];

  const int tid  = threadIdx.x;
  const int wv   = tid >> 6;      // 0..15, owns m-tile wv in every stage
  const int lane = tid & 63;
  const int lq   = lane >> 4, l15 = lane & 15;
  const int n0   = blockIdx.x * 16;
  const int mt   = wv;

  if (tid < 256) {
    lb[0 * 256 + tid] = bhp[tid];
    lb[1 * 256 + tid] = bcp[tid];
    lb[2 * 256 + tid] = bm[tid];
    lb[3 * 256 + tid] = bhpost[tid];
    lb[4 * 256 + tid] = br1[tid];
    lb[5 * 256 + tid] = Wr2[tid];
  }
  for (int i = tid; i < 8 * 512; i += 1024) hB[i] = (__bf16)0.0f;  // h0 = 0
  const float br2v = br2[0];

  // bias accessor: element r of f32x4 <-> feature 16*mt + 4*lq + r
  #define BIAS(a) (*(const f32x4*)(lb + (a) * 256 + mt * 16 + 4 * lq))
  const f32x4 w2v = *(const f32x4*)(Wr2 + mt * 16 + 4 * lq);

  const __bf16* hp_p = wsp + OFF_HP + (size_t)(mt * 8) * 512 + lane * 8;
  const __bf16* r1_p = wsp + OFF_R1 + (size_t)(mt * 8) * 512 + lane * 8;
  const __bf16* cp_p = wsp + OFF_CP + (size_t)(mt * 2) * 512 + lane * 8;
  const __bf16* po_p = wsp + OFF_PO + (size_t)(mt * 8) * 512 + lane * 8;
  const __bf16* wm_p = wsp + OFF_M  + (size_t)(mt * 16) * 512 + lane * 8;

  // x for step 0 + hp/cp windows for step 0 (drained at the init barrier)
  const float* xbase = x + (size_t)(n0 + l15) * 64 + 8 * lq;
  f32x4 xr0 = *(const f32x4*)(xbase);
  f32x4 xr1 = *(const f32x4*)(xbase + 4);
  f32x4 xr2 = *(const f32x4*)(xbase + 32);
  f32x4 xr3 = *(const f32x4*)(xbase + 36);
  bf16x8 hpw[8], cpw[2];
  #pragma unroll
  for (int p = 0; p < 8; ++p) hpw[p] = *(const bf16x8*)(hp_p + p * 512);
  cpw[0] = *(const bf16x8*)(cp_p);
  cpw[1] = *(const bf16x8*)(cp_p + 512);

  __syncthreads();

  for (int t = 0; t < TT; ++t) {
    bf16x8 Bx0, Bx1;
    #pragma unroll
    for (int j = 0; j < 4; ++j) {
      Bx0[j] = (__bf16)xr0[j]; Bx0[4 + j] = (__bf16)xr1[j];
      Bx1[j] = (__bf16)xr2[j]; Bx1[4 + j] = (__bf16)xr3[j];
    }

    // ---- stage 1: hp = h@Whp+bhp ; cp = x@Wcp+bcp ; r1 = h@Wr1+br1 ----
    bf16x8 Bh[8];
    #pragma unroll
    for (int kt = 0; kt < 8; ++kt)
      Bh[kt] = *(const bf16x8*)(hB + kt * 512 + lane * 8);
    f32x4 ah = BIAS(0);
    #pragma unroll
    for (int kt = 0; kt < 8; ++kt) ah = MFMA(hpw[kt], Bh[kt], ah);
    // r1 window issues here; its ~250cy latency hides under tanh/pack below
    bf16x8 r1w[8];
    #pragma unroll
    for (int p = 0; p < 8; ++p) r1w[p] = *(const bf16x8*)(r1_p + p * 512);
    f32x4 ac = BIAS(1);
    ac = MFMA(cpw[0], Bx0, ac);
    ac = MFMA(cpw[1], Bx1, ac);
    pack4(mB, mt, lane, ah);
    pack4(mB + 8 * 512, mt, lane, ac);
    f32x4 ar = BIAS(4);
    #pragma unroll
    for (int kt = 0; kt < 8; ++kt) ar = MFMA(r1w[kt], Bh[kt], ar);
    {
      float p = 0.f;
      #pragma unroll
      for (int r = 0; r < 4; ++r) p += fmaxf(ar[r], 0.f) * w2v[r];
      p += __shfl_xor(p, 16, 64);
      p += __shfl_xor(p, 32, 64);
      if (lane < 16) outp[wv * 16 + lane] = p;
    }
    // pre-issue first half of mesh weights; drain lands inside B1
    bf16x8 wmw[8];
    #pragma unroll
    for (int p = 0; p < 8; ++p) wmw[p] = *(const bf16x8*)(wm_p + p * 512);
    __syncthreads();  // B1

    // ---- stage 2: u = cat @ Wm + bm ; store out[t-1] ----
    if (t > 0 && tid < 16) {
      float s = br2v;
      #pragma unroll
      for (int w = 0; w < 16; ++w) s += outp[w * 16 + tid];
      out[(size_t)(t - 1) * NB + n0 + tid] = s;
    }
    f32x4 am = BIAS(2);
    #pragma unroll
    for (int i = 0; i < 16; ++i) {
      bf16x8 Bm = *(const bf16x8*)(mB + i * 512 + lane * 8);
      am = MFMA(wmw[i & 7], Bm, am);
      if (i + 8 < 16) wmw[i & 7] = *(const bf16x8*)(wm_p + (i + 8) * 512);
    }
    pack4(uB, mt, lane, am);
    // pre-issue po frags; drain lands inside B2
    bf16x8 pow_[8];
    #pragma unroll
    for (int p = 0; p < 8; ++p) pow_[p] = *(const bf16x8*)(po_p + p * 512);
    __syncthreads();  // B2

    // ---- stage 3: h = tanh(u @ Whpost + bhpost) ----
    bf16x8 Bu[8];
    #pragma unroll
    for (int kt = 0; kt < 8; ++kt)
      Bu[kt] = *(const bf16x8*)(uB + kt * 512 + lane * 8);
    f32x4 ap = BIAS(3);
    #pragma unroll
    for (int kt = 0; kt < 8; ++kt) ap = MFMA(pow_[kt], Bu[kt], ap);
    // prefetch next step's x + hp/cp windows; drain lands inside B3
    {
      int tn = (t + 1 < TT) ? t + 1 : TT - 1;
      const float* xp = xbase + (size_t)tn * NB * 64;
      xr0 = *(const f32x4*)(xp);      xr1 = *(const f32x4*)(xp + 4);
      xr2 = *(const f32x4*)(xp + 32); xr3 = *(const f32x4*)(xp + 36);
    }
    #pragma unroll
    for (int p = 0; p < 8; ++p) hpw[p] = *(const bf16x8*)(hp_p + p * 512);
    cpw[0] = *(const bf16x8*)(cp_p);
    cpw[1] = *(const bf16x8*)(cp_p + 512);
    pack4(hB, mt, lane, ap);
    __syncthreads();  // B3
  }

  // ---- tail: regressor on final h ----
  {
    bf16x8 Bh[8];
    #pragma unroll
    for (int kt = 0; kt < 8; ++kt)
      Bh[kt] = *(const bf16x8*)(hB + kt * 512 + lane * 8);
    bf16x8 r1w[8];
    #pragma unroll
    for (int p = 0; p < 8; ++p) r1w[p] = *(const bf16x8*)(r1_p + p * 512);
    f32x4 ar = BIAS(4);
    #pragma unroll
    for (int kt = 0; kt < 8; ++kt) ar = MFMA(r1w[kt], Bh[kt], ar);
    float p = 0.f;
    #pragma unroll
    for (int r = 0; r < 4; ++r) p += fmaxf(ar[r], 0.f) * w2v[r];
    p += __shfl_xor(p, 16, 64);
    p += __shfl_xor(p, 32, 64);
    if (lane < 16) outp[wv * 16 + lane] = p;
    __syncthreads();
    if (tid < 16) {
      float s = br2v;
      #pragma unroll
      for (int w = 0; w < 16; ++w) s += outp[w * 16 + tid];
      out[(size_t)(TT - 1) * NB + n0 + tid] = s;
    }
  }
}

extern "C" void kernel_launch(void* const* d_in, const int* in_sizes, int n_in,
                              void* d_out, int out_size, void* d_ws, size_t ws_size,
                              hipStream_t stream) {
  const float* x      = (const float*)d_in[0];
  const float* Whp    = (const float*)d_in[1];
  const float* bhp    = (const float*)d_in[2];
  const float* Wcp    = (const float*)d_in[3];
  const float* bcp    = (const float*)d_in[4];
  const float* Wm     = (const float*)d_in[5];
  const float* bm     = (const float*)d_in[6];
  const float* Whpost = (const float*)d_in[7];
  const float* bhpost = (const float*)d_in[8];
  const float* Wr1    = (const float*)d_in[9];
  const float* br1    = (const float*)d_in[10];
  const float* Wr2    = (const float*)d_in[11];
  const float* br2    = (const float*)d_in[12];
  __bf16* wsp = (__bf16*)d_ws;
  float*  out = (float*)d_out;

  if (ws_size < (size_t)TOT * sizeof(__bf16)) return;

  pack_weights<<<(TOT + 255) / 256, 256, 0, stream>>>(Whp, Wm, Wcp, Whpost, Wr1, wsp);
  rnn_seq<<<64, 1024, 0, stream>>>(x, wsp, bhp, bcp, bm, bhpost, br1, Wr2, br2, out);
}